// Round 1
// baseline (41.359 us; speedup 1.0000x reference)
//
#include <hip/hip_runtime.h>
#include <hip/hip_bf16.h>

#define N_ROWS 2048
#define D_IN   256
#define D_OUT  64
#define JS     16        // j-splits for kernel 2
#define ALPHA  0.2f
#define LN_EPS 1e-5f

typedef __attribute__((ext_vector_type(4))) float f32x4;
typedef __attribute__((ext_vector_type(8))) short s16x8;

static __device__ __forceinline__ unsigned short f2bf(float x) {
    unsigned u = __float_as_uint(x);
    unsigned r = (u + 0x7FFFu + ((u >> 16) & 1u)) >> 16;   // RTN-even
    return (unsigned short)r;
}
static __device__ __forceinline__ float bf2f(unsigned short u) {
    return __uint_as_float(((unsigned)u) << 16);
}

// ---------------------------------------------------------------------------
// K1: h = LN(F @ phiW^T + phiB); s = h . muW; write H^T in bf16 hi/lo planes.
// grid 256 blocks x 128 threads; block = 8 rows (2 waves x 4 rows/wave).
// phiW staged in LDS in two 32KB halves, XOR-swizzled for conflict-free b128.
// ---------------------------------------------------------------------------
__global__ __launch_bounds__(128) void k1_h_s(
    const float* __restrict__ F, const float* __restrict__ phiW,
    const float* __restrict__ phiB, const float* __restrict__ lnG,
    const float* __restrict__ lnB, const float* __restrict__ muW,
    float* __restrict__ s_out, unsigned short* __restrict__ HhiT,
    unsigned short* __restrict__ HloT)
{
    __shared__ f32x4 phiS[64 * 32];          // 32 KB (one k-half)
    __shared__ unsigned short Thi[64][8];
    __shared__ unsigned short Tlo[64][8];

    const int tid  = threadIdx.x;
    const int w    = tid >> 6;
    const int lane = tid & 63;
    const int i_base = blockIdx.x * 8;
    const int r0 = i_base + w * 4;

    const f32x4* phiW4 = (const f32x4*)phiW;   // [64][64] float4 row-major
    const f32x4* F4    = (const f32x4*)F;      // [2048][64] float4

    float acc[4] = {0.f, 0.f, 0.f, 0.f};

    for (int half = 0; half < 2; ++half) {
        for (int idx = tid; idx < 64 * 32; idx += 128) {
            int d = idx >> 5, g = idx & 31;
            phiS[(d << 5) | (g ^ (d & 7))] = phiW4[d * 64 + half * 32 + g];
        }
        __syncthreads();
        for (int g = 0; g < 32; ++g) {
            f32x4 p = phiS[(lane << 5) | (g ^ (lane & 7))];
            #pragma unroll
            for (int rr = 0; rr < 4; ++rr) {
                f32x4 f = F4[(r0 + rr) * 64 + half * 32 + g];
                acc[rr] += p.x * f.x + p.y * f.y + p.z * f.z + p.w * f.w;
            }
        }
        __syncthreads();
    }

    const float pb = phiB[lane], gg = lnG[lane], bb = lnB[lane], mw = muW[lane];

    #pragma unroll
    for (int rr = 0; rr < 4; ++rr) {
        float h = acc[rr] + pb;
        float m = h;
        #pragma unroll
        for (int off = 32; off >= 1; off >>= 1) m += __shfl_xor(m, off);
        m *= (1.f / 64.f);
        float c = h - m;
        float v = c * c;
        #pragma unroll
        for (int off = 32; off >= 1; off >>= 1) v += __shfl_xor(v, off);
        v *= (1.f / 64.f);
        float hn = c * rsqrtf(v + LN_EPS) * gg + bb;
        float sp = hn * mw;
        #pragma unroll
        for (int off = 32; off >= 1; off >>= 1) sp += __shfl_xor(sp, off);
        if (lane == 0) s_out[r0 + rr] = sp;
        unsigned short hi = f2bf(hn);
        unsigned short lo = f2bf(hn - bf2f(hi));
        Thi[lane][w * 4 + rr] = hi;
        Tlo[lane][w * 4 + rr] = lo;
    }
    __syncthreads();
    {   // coalesced-ish transposed store: H^T[d][i_base .. i_base+7]
        int d = tid >> 1, half = tid & 1;
        ushort4 vh = *(const ushort4*)&Thi[d][half * 4];
        *(ushort4*)&HhiT[d * N_ROWS + i_base + half * 4] = vh;
        ushort4 vl = *(const ushort4*)&Tlo[d][half * 4];
        *(ushort4*)&HloT[d * N_ROWS + i_base + half * 4] = vl;
    }
}

// ---------------------------------------------------------------------------
// K2: per block (1 wave): 16 output rows x 128-j slab of one j-split.
// Build W = exp(leakyrelu(s_i+s_j+mu_b)) [masked] in LDS as bf16, then MFMA:
// numerator partial = W @ (Hhi + Hlo), denominator partial l = W @ ones.
// grid (2048/16)*JS = 2048 blocks x 64 threads.
// ---------------------------------------------------------------------------
__global__ __launch_bounds__(64) void k2_attn(
    const int* __restrict__ adj, const float* __restrict__ s,
    const unsigned short* __restrict__ HhiT, const unsigned short* __restrict__ HloT,
    const float* __restrict__ muB,
    float* __restrict__ num_p, float* __restrict__ l_p)
{
    const int lane = threadIdx.x;
    const int mb = blockIdx.x >> 4;           // 0..127
    const int js = blockIdx.x & (JS - 1);     // 0..15
    const int i0 = mb * 16;
    const int j0 = js * (N_ROWS / JS);
    const float mub = muB[0];

    __shared__ __align__(16) unsigned short Wt[16][72];   // padded rows (144 B)

    f32x4 accN[4];
    f32x4 accL;
    #pragma unroll
    for (int nb = 0; nb < 4; ++nb) { accN[nb][0]=0.f; accN[nb][1]=0.f; accN[nb][2]=0.f; accN[nb][3]=0.f; }
    accL[0]=0.f; accL[1]=0.f; accL[2]=0.f; accL[3]=0.f;

    s16x8 ones;
    #pragma unroll
    for (int e = 0; e < 8; ++e) ones[e] = (short)0x3F80;  // bf16 1.0

    const int rsel = lane & 15;     // row within 16 (A) / col d within 16 (B,C)
    const int ksel = lane >> 4;     // k-chunk selector

    #pragma unroll
    for (int kt = 0; kt < (N_ROWS / JS) / 64; ++kt) {
        const int jb = j0 + kt * 64;
        const float sj = s[jb + lane];
        // ---- build 16x64 W tile (coalesced adj reads, one exp per element)
        #pragma unroll
        for (int rr = 0; rr < 16; ++rr) {
            const int i = i0 + rr;
            const float si = s[i];
            const int a = adj[(size_t)i * N_ROWS + jb + lane];
            const float z = si + sj + mub;
            const float e = z > 0.f ? z : ALPHA * z;
            const float wv = a ? __expf(e) : 0.f;
            Wt[rr][lane] = f2bf(wv);
        }
        __syncthreads();
        // ---- A fragments from LDS (row = lane&15, k = (lane>>4)*8 + e)
        s16x8 a0 = *(const s16x8*)&Wt[rsel][ksel * 8];
        s16x8 a1 = *(const s16x8*)&Wt[rsel][32 + ksel * 8];
        // denominator: W @ ones
        accL = __builtin_amdgcn_mfma_f32_16x16x32_bf16(a0, ones, accL, 0, 0, 0);
        accL = __builtin_amdgcn_mfma_f32_16x16x32_bf16(a1, ones, accL, 0, 0, 0);
        // numerator: W @ Hhi + W @ Hlo  (B frags straight from global H^T, L2-hot)
        #pragma unroll
        for (int nb = 0; nb < 4; ++nb) {
            const unsigned short* hr = HhiT + (size_t)(nb * 16 + rsel) * N_ROWS + jb + ksel * 8;
            s16x8 b0 = *(const s16x8*)hr;
            s16x8 b1 = *(const s16x8*)(hr + 32);
            accN[nb] = __builtin_amdgcn_mfma_f32_16x16x32_bf16(a0, b0, accN[nb], 0, 0, 0);
            accN[nb] = __builtin_amdgcn_mfma_f32_16x16x32_bf16(a1, b1, accN[nb], 0, 0, 0);
            const unsigned short* lr = HloT + (size_t)(nb * 16 + rsel) * N_ROWS + jb + ksel * 8;
            s16x8 c0 = *(const s16x8*)lr;
            s16x8 c1 = *(const s16x8*)(lr + 32);
            accN[nb] = __builtin_amdgcn_mfma_f32_16x16x32_bf16(a0, c0, accN[nb], 0, 0, 0);
            accN[nb] = __builtin_amdgcn_mfma_f32_16x16x32_bf16(a1, c1, accN[nb], 0, 0, 0);
        }
        __syncthreads();
    }

    // ---- store partials: C layout col = lane&15, row = (lane>>4)*4 + reg
    float* np = num_p + (size_t)js * (N_ROWS * D_OUT);
    #pragma unroll
    for (int nb = 0; nb < 4; ++nb) {
        #pragma unroll
        for (int r = 0; r < 4; ++r) {
            const int row = i0 + ksel * 4 + r;
            np[row * D_OUT + nb * 16 + rsel] = accN[nb][r];
        }
    }
    if (rsel == 0) {
        #pragma unroll
        for (int r = 0; r < 4; ++r)
            l_p[js * N_ROWS + i0 + ksel * 4 + r] = accL[r];
    }
}

// ---------------------------------------------------------------------------
// K3: combine j-split partials, normalize, ELU.
// ---------------------------------------------------------------------------
__global__ __launch_bounds__(256) void k3_combine(
    const float* __restrict__ num_p, const float* __restrict__ l_p,
    float* __restrict__ out)
{
    const int g = blockIdx.x * 256 + threadIdx.x;
    const int i = g >> 6;
    float num = 0.f, l = 0.f;
    #pragma unroll
    for (int js = 0; js < JS; ++js) {
        num += num_p[(size_t)js * (N_ROWS * D_OUT) + g];
        l   += l_p[js * N_ROWS + i];
    }
    const float o = num / l;
    out[g] = o > 0.f ? o : expm1f(o);
}

// ---------------------------------------------------------------------------
extern "C" void kernel_launch(void* const* d_in, const int* in_sizes, int n_in,
                              void* d_out, int out_size, void* d_ws, size_t ws_size,
                              hipStream_t stream)
{
    const float* F    = (const float*)d_in[0];
    const int*   adj  = (const int*)d_in[1];
    const float* phiW = (const float*)d_in[2];
    const float* phiB = (const float*)d_in[3];
    const float* lnG  = (const float*)d_in[4];
    const float* lnB  = (const float*)d_in[5];
    const float* muW  = (const float*)d_in[6];
    const float* muB  = (const float*)d_in[7];
    float* out = (float*)d_out;

    float* ws   = (float*)d_ws;
    float* s    = ws;                                   // 2048 f32
    float* l_p  = ws + N_ROWS;                          // JS*2048 f32
    float* numP = l_p + (size_t)JS * N_ROWS;            // JS*2048*64 f32
    unsigned short* HhiT = (unsigned short*)(numP + (size_t)JS * N_ROWS * D_OUT); // 64*2048 bf16
    unsigned short* HloT = HhiT + (size_t)D_OUT * N_ROWS;                         // 64*2048 bf16

    k1_h_s<<<dim3(N_ROWS / 8), dim3(128), 0, stream>>>(F, phiW, phiB, lnG, lnB, muW,
                                                       s, HhiT, HloT);
    k2_attn<<<dim3((N_ROWS / 16) * JS), dim3(64), 0, stream>>>(adj, s, HhiT, HloT, muB,
                                                               numP, l_p);
    k3_combine<<<dim3((N_ROWS * D_OUT) / 256), dim3(256), 0, stream>>>(numP, l_p, out);
}

// Round 2
// 27.129 us; speedup vs baseline: 1.5245x; 1.5245x over previous
//
#include <hip/hip_runtime.h>
#include <hip/hip_bf16.h>

#define N_ROWS 2048
#define D_IN   256
#define D_OUT  64
#define JSLAB  8         // j-slabs for kernel 2 (each 256 j = 4 waves x 64 j)
#define ALPHA  0.2f
#define LN_EPS 1e-5f

typedef __attribute__((ext_vector_type(4))) float f32x4;
typedef __attribute__((ext_vector_type(8))) short s16x8;

static __device__ __forceinline__ unsigned short f2bf(float x) {
    unsigned u = __float_as_uint(x);
    unsigned r = (u + 0x7FFFu + ((u >> 16) & 1u)) >> 16;   // RTN-even
    return (unsigned short)r;
}
static __device__ __forceinline__ float bf2f(unsigned short u) {
    return __uint_as_float(((unsigned)u) << 16);
}

// ---------------------------------------------------------------------------
// K1: h = LN(F @ phiW^T + phiB); s = h . muW; write H^T in bf16 hi/lo planes.
// grid 256 blocks x 256 threads; block = 8 rows (4 waves x 2 rows/wave).
// Full phiW (64 KB) staged once in LDS, XOR-swizzled for conflict-free b128.
// ---------------------------------------------------------------------------
__global__ __launch_bounds__(256) void k1_h_s(
    const float* __restrict__ F, const float* __restrict__ phiW,
    const float* __restrict__ phiB, const float* __restrict__ lnG,
    const float* __restrict__ lnB, const float* __restrict__ muW,
    float* __restrict__ s_out, unsigned short* __restrict__ HhiT,
    unsigned short* __restrict__ HloT)
{
    __shared__ f32x4 phiS[64 * 64];          // 64 KB
    __shared__ unsigned short Thi[64][8];
    __shared__ unsigned short Tlo[64][8];

    const int tid  = threadIdx.x;
    const int w    = tid >> 6;
    const int lane = tid & 63;
    const int i_base = blockIdx.x * 8;
    const int r0 = i_base + w * 2;

    const f32x4* phiW4 = (const f32x4*)phiW;   // [64][64] float4 row-major
    const f32x4* F4    = (const f32x4*)F;      // [2048][64] float4

    #pragma unroll
    for (int t = 0; t < 16; ++t) {
        int idx = tid + t * 256;
        int d = idx >> 6, g = idx & 63;
        phiS[(d << 6) | (g ^ (d & 7))] = phiW4[idx];
    }
    __syncthreads();

    float acc[2] = {0.f, 0.f};
    for (int g = 0; g < 64; ++g) {
        f32x4 p = phiS[(lane << 6) | (g ^ (lane & 7))];
        #pragma unroll
        for (int rr = 0; rr < 2; ++rr) {
            f32x4 f = F4[(r0 + rr) * 64 + g];
            acc[rr] += p.x * f.x + p.y * f.y + p.z * f.z + p.w * f.w;
        }
    }

    const float pb = phiB[lane], gg = lnG[lane], bb = lnB[lane], mw = muW[lane];

    #pragma unroll
    for (int rr = 0; rr < 2; ++rr) {
        float h = acc[rr] + pb;
        float m = h;
        #pragma unroll
        for (int off = 32; off >= 1; off >>= 1) m += __shfl_xor(m, off);
        m *= (1.f / 64.f);
        float c = h - m;
        float v = c * c;
        #pragma unroll
        for (int off = 32; off >= 1; off >>= 1) v += __shfl_xor(v, off);
        v *= (1.f / 64.f);
        float hn = c * rsqrtf(v + LN_EPS) * gg + bb;
        float sp = hn * mw;
        #pragma unroll
        for (int off = 32; off >= 1; off >>= 1) sp += __shfl_xor(sp, off);
        if (lane == 0) s_out[r0 + rr] = sp;
        unsigned short hi = f2bf(hn);
        unsigned short lo = f2bf(hn - bf2f(hi));
        Thi[lane][w * 2 + rr] = hi;
        Tlo[lane][w * 2 + rr] = lo;
    }
    __syncthreads();
    if (tid < 128) {   // transposed store: H^T[d][i_base .. i_base+7]
        int d = tid >> 1, half = tid & 1;
        ushort4 vh = *(const ushort4*)&Thi[d][half * 4];
        *(ushort4*)&HhiT[d * N_ROWS + i_base + half * 4] = vh;
        ushort4 vl = *(const ushort4*)&Tlo[d][half * 4];
        *(ushort4*)&HloT[d * N_ROWS + i_base + half * 4] = vl;
    }
}

// ---------------------------------------------------------------------------
// K2: block = 4 waves; block covers 16 rows x 256 j; wave w owns 16x64 tile.
// Build W = exp(leakyrelu(s_i+s_j+mu_b)) [masked] per-wave in LDS (no barrier
// needed: same-wave LDS write->read), MFMA numerator + ones-denominator,
// cross-wave LDS combine, write one partial per slab.
// grid 128*JSLAB = 1024 blocks x 256 threads -> 4096 waves (16/CU).
// ---------------------------------------------------------------------------
__global__ __launch_bounds__(256) void k2_attn(
    const int* __restrict__ adj, const float* __restrict__ s,
    const unsigned short* __restrict__ HhiT, const unsigned short* __restrict__ HloT,
    const float* __restrict__ muB,
    float* __restrict__ num_p, float* __restrict__ l_p)
{
    const int tid  = threadIdx.x;
    const int w    = tid >> 6;
    const int lane = tid & 63;
    const int stripe = blockIdx.x >> 3;        // 0..127
    const int slab   = blockIdx.x & (JSLAB - 1);
    const int i0 = stripe * 16;
    const int jb = slab * 256 + w * 64;
    const float mub = muB[0];

    __shared__ __align__(16) unsigned short Wt[4][16][72];
    __shared__ f32x4 cN[4][4][64];     // [wave][nb][lane]
    __shared__ f32x4 cL[4][64];

    const int rsel = lane & 15;
    const int rsub = lane >> 4;        // 0..3

    f32x4 accN[4];
    f32x4 accL;
    #pragma unroll
    for (int nb = 0; nb < 4; ++nb) { accN[nb][0]=0.f; accN[nb][1]=0.f; accN[nb][2]=0.f; accN[nb][3]=0.f; }
    accL[0]=0.f; accL[1]=0.f; accL[2]=0.f; accL[3]=0.f;

    s16x8 ones;
    #pragma unroll
    for (int e = 0; e < 8; ++e) ones[e] = (short)0x3F80;  // bf16 1.0

    // ---- build 16x64 W tile: int4 adj loads (16B/lane), 4 rows/iteration
    const float4 sj4 = ((const float4*)s)[(jb >> 2) + rsel];
    const int4* adj4 = (const int4*)adj;
    #pragma unroll
    for (int r4 = 0; r4 < 4; ++r4) {
        const int row = r4 * 4 + rsub;
        const int i = i0 + row;
        const float si = s[i];
        int4 a = adj4[(size_t)i * (N_ROWS / 4) + (jb >> 2) + rsel];
        ushort4 pk;
        {
            float z = si + sj4.x + mub; float e = z > 0.f ? z : ALPHA * z;
            pk.x = a.x ? f2bf(__expf(e)) : 0;
        }{
            float z = si + sj4.y + mub; float e = z > 0.f ? z : ALPHA * z;
            pk.y = a.y ? f2bf(__expf(e)) : 0;
        }{
            float z = si + sj4.z + mub; float e = z > 0.f ? z : ALPHA * z;
            pk.z = a.z ? f2bf(__expf(e)) : 0;
        }{
            float z = si + sj4.w + mub; float e = z > 0.f ? z : ALPHA * z;
            pk.w = a.w ? f2bf(__expf(e)) : 0;
        }
        *(ushort4*)&Wt[w][row][rsel * 4] = pk;
    }

    // ---- A fragments (same-wave LDS dependency; compiler emits lgkmcnt)
    s16x8 a0 = *(const s16x8*)&Wt[w][rsel][rsub * 8];
    s16x8 a1 = *(const s16x8*)&Wt[w][rsel][32 + rsub * 8];

    accL = __builtin_amdgcn_mfma_f32_16x16x32_bf16(a0, ones, accL, 0, 0, 0);
    accL = __builtin_amdgcn_mfma_f32_16x16x32_bf16(a1, ones, accL, 0, 0, 0);
    #pragma unroll
    for (int nb = 0; nb < 4; ++nb) {
        const unsigned short* hr = HhiT + (size_t)(nb * 16 + rsel) * N_ROWS + jb + rsub * 8;
        s16x8 b0 = *(const s16x8*)hr;
        s16x8 b1 = *(const s16x8*)(hr + 32);
        accN[nb] = __builtin_amdgcn_mfma_f32_16x16x32_bf16(a0, b0, accN[nb], 0, 0, 0);
        accN[nb] = __builtin_amdgcn_mfma_f32_16x16x32_bf16(a1, b1, accN[nb], 0, 0, 0);
        const unsigned short* lr = HloT + (size_t)(nb * 16 + rsel) * N_ROWS + jb + rsub * 8;
        s16x8 c0 = *(const s16x8*)lr;
        s16x8 c1 = *(const s16x8*)(lr + 32);
        accN[nb] = __builtin_amdgcn_mfma_f32_16x16x32_bf16(a0, c0, accN[nb], 0, 0, 0);
        accN[nb] = __builtin_amdgcn_mfma_f32_16x16x32_bf16(a1, c1, accN[nb], 0, 0, 0);
    }

    // ---- cross-wave combine
    #pragma unroll
    for (int nb = 0; nb < 4; ++nb) cN[w][nb][lane] = accN[nb];
    cL[w][lane] = accL;
    __syncthreads();

    {   // wave w handles column-block nb = w
        f32x4 n = cN[0][w][lane] + cN[1][w][lane] + cN[2][w][lane] + cN[3][w][lane];
        float* np = num_p + (size_t)slab * (N_ROWS * D_OUT);
        #pragma unroll
        for (int r = 0; r < 4; ++r)
            np[(i0 + rsub * 4 + r) * D_OUT + w * 16 + rsel] = n[r];
    }
    if (w == 0) {
        f32x4 l = cL[0][lane] + cL[1][lane] + cL[2][lane] + cL[3][lane];
        if (rsel == 0) {
            #pragma unroll
            for (int r = 0; r < 4; ++r)
                l_p[slab * N_ROWS + i0 + rsub * 4 + r] = l[r];
        }
    }
}

// ---------------------------------------------------------------------------
// K3: combine j-slab partials, normalize, ELU.
// ---------------------------------------------------------------------------
__global__ __launch_bounds__(256) void k3_combine(
    const float* __restrict__ num_p, const float* __restrict__ l_p,
    float* __restrict__ out)
{
    const int g = blockIdx.x * 256 + threadIdx.x;
    const int i = g >> 6;
    float num = 0.f, l = 0.f;
    #pragma unroll
    for (int js = 0; js < JSLAB; ++js) {
        num += num_p[(size_t)js * (N_ROWS * D_OUT) + g];
        l   += l_p[js * N_ROWS + i];
    }
    const float o = num / l;
    out[g] = o > 0.f ? o : expm1f(o);
}

// ---------------------------------------------------------------------------
extern "C" void kernel_launch(void* const* d_in, const int* in_sizes, int n_in,
                              void* d_out, int out_size, void* d_ws, size_t ws_size,
                              hipStream_t stream)
{
    const float* F    = (const float*)d_in[0];
    const int*   adj  = (const int*)d_in[1];
    const float* phiW = (const float*)d_in[2];
    const float* phiB = (const float*)d_in[3];
    const float* lnG  = (const float*)d_in[4];
    const float* lnB  = (const float*)d_in[5];
    const float* muW  = (const float*)d_in[6];
    const float* muB  = (const float*)d_in[7];
    float* out = (float*)d_out;

    float* ws   = (float*)d_ws;
    float* s    = ws;                                   // 2048 f32
    float* l_p  = ws + N_ROWS;                          // JSLAB*2048 f32
    float* numP = l_p + (size_t)JSLAB * N_ROWS;         // JSLAB*2048*64 f32
    unsigned short* HhiT = (unsigned short*)(numP + (size_t)JSLAB * N_ROWS * D_OUT);
    unsigned short* HloT = HhiT + (size_t)D_OUT * N_ROWS;

    k1_h_s<<<dim3(N_ROWS / 8), dim3(256), 0, stream>>>(F, phiW, phiB, lnG, lnB, muW,
                                                       s, HhiT, HloT);
    k2_attn<<<dim3((N_ROWS / 16) * JSLAB), dim3(256), 0, stream>>>(adj, s, HhiT, HloT, muB,
                                                                   numP, l_p);
    k3_combine<<<dim3((N_ROWS * D_OUT) / 256), dim3(256), 0, stream>>>(numP, l_p, out);
}